// Round 6
// baseline (228.426 us; speedup 1.0000x reference)
//
#include <hip/hip_runtime.h>

#define Bz 4
#define Tz 4096
#define Ez 1024
#define Hz 16
#define Sz 64
#define Dz 64
#define MTz (Bz*Tz)   // 16384

using f32x4  = __attribute__((ext_vector_type(4))) float;
using short8 = __attribute__((ext_vector_type(8))) short;

__device__ __forceinline__ unsigned f2bf(float f){
  unsigned u = __builtin_bit_cast(unsigned, f);
  u = u + 0x7FFFu + ((u >> 16) & 1u);
  return (u >> 16);
}

#define GLL16(gp, lp) __builtin_amdgcn_global_load_lds( \
    (const __attribute__((address_space(1))) unsigned int*)(gp), \
    (__attribute__((address_space(3))) unsigned int*)(lp), 16, 0, 0)

// ---------------- PRE: one kernel, 260 blocks ----------------------------------------
// blk 0..255  : (h = blk>>4, ec = blk&15) -> Mh[h] in LDS -> Wb[ec*64..+63][h*64..+63]
// blk 256..259: b = blk-256 -> a_state -> bias_f (LDS) -> constb
__global__ __launch_bounds__(256) void pre_all(const float* __restrict__ state,
                                               const float* __restrict__ A_w,
                                               const float* __restrict__ A_b,
                                               const float* __restrict__ C_w,
                                               const float* __restrict__ C_b,
                                               const float* __restrict__ sm,
                                               const float* __restrict__ Wo,
                                               const float* __restrict__ bo,
                                               float* __restrict__ a_state,
                                               float* __restrict__ constb,
                                               unsigned short* __restrict__ Wb){
  const int blk = blockIdx.x, tid = threadIdx.x;
  if (blk < 256){
    __shared__ float Mh_l[64][64];              // 16 KiB
    const int h = blk >> 4, ec = blk & 15;
    const int dp = tid & 63, g = tid >> 6;      // g in 0..3
    const float* smh = sm + (size_t)h*4096;
    #pragma unroll 4
    for (int dd = 0; dd < 16; ++dd){
      const int d = g*16 + dd;
      const float* cw = C_w + (size_t)(h*64 + d)*64;
      float a0=0.f,a1=0.f,a2=0.f,a3=0.f;
      #pragma unroll 4
      for (int s = 0; s < 64; s += 4){
        a0 += cw[s]*smh[s*64+dp];     a1 += cw[s+1]*smh[(s+1)*64+dp];
        a2 += cw[s+2]*smh[(s+2)*64+dp]; a3 += cw[s+3]*smh[(s+3)*64+dp];
      }
      Mh_l[d][dp] = (a0+a1)+(a2+a3);
    }
    __syncthreads();
    #pragma unroll 4
    for (int ee = 0; ee < 16; ++ee){
      const int e = ec*64 + g*16 + ee;
      const float* wo = Wo + (size_t)e*1024 + h*64;
      float a0=0.f,a1=0.f,a2=0.f,a3=0.f;
      #pragma unroll 4
      for (int d = 0; d < 64; d += 4){
        a0 += wo[d]*Mh_l[d][dp];   a1 += wo[d+1]*Mh_l[d+1][dp];
        a2 += wo[d+2]*Mh_l[d+2][dp]; a3 += wo[d+3]*Mh_l[d+3][dp];
      }
      Wb[(size_t)e*1024 + h*64 + dp] = (unsigned short)f2bf((a0+a1)+(a2+a3));
    }
  } else {
    __shared__ float asl[16][64];               // a_state[h][s] for this b
    __shared__ float bfl[1024];                 // bias_f[b][*]
    const int b = blk - 256;
    #pragma unroll
    for (int r = 0; r < 4; ++r){
      int o = r*256 + tid;                      // h*64+s
      int h = o >> 6, s = o & 63;
      const float* aw = A_w + (size_t)o*64;
      const float* st = state + (size_t)(h*4 + b)*64;
      float a0=A_b[o],a1=0.f,a2=0.f,a3=0.f;
      #pragma unroll 4
      for (int j = 0; j < 64; j += 4){
        a0 += aw[j]*st[j];     a1 += aw[j+1]*st[j+1];
        a2 += aw[j+2]*st[j+2]; a3 += aw[j+3]*st[j+3];
      }
      float v = (a0+a1)+(a2+a3);
      a_state[(h*4 + b)*64 + s] = v;
      asl[h][s] = v;
    }
    __syncthreads();
    #pragma unroll
    for (int r = 0; r < 4; ++r){
      int f = r*256 + tid;                      // h*64+d
      int h = f >> 6;
      const float* cw = C_w + (size_t)f*64;
      float a0=C_b[f],a1=0.f,a2=0.f,a3=0.f;
      #pragma unroll 4
      for (int s = 0; s < 64; s += 4){
        a0 += cw[s]*asl[h][s];     a1 += cw[s+1]*asl[h][s+1];
        a2 += cw[s+2]*asl[h][s+2]; a3 += cw[s+3]*asl[h][s+3];
      }
      bfl[f] = (a0+a1)+(a2+a3);
    }
    __syncthreads();
    #pragma unroll
    for (int r = 0; r < 4; ++r){
      int e = r*256 + tid;
      const float4* wo = (const float4*)(Wo + (size_t)e*1024);
      float ax=0.f,ay=0.f,az=0.f,aw=0.f;
      for (int f4 = 0; f4 < 256; ++f4){
        float4 w = wo[f4];
        float4 v = *(const float4*)&bfl[f4*4];
        ax += w.x*v.x; ay += w.y*v.y; az += w.z*v.z; aw += w.w*v.w;
      }
      constb[b*1024 + e] = bo[e] + ((ax+ay)+(az+aw));
    }
  }
}

// ---------------- K4: new_state (MFMA, swapped operands) + emit xb=bf16(x) -----------
// grid: b(4) x h(16) x tb(32) = 2048 blocks, 256 thr, tile 128(t) x 64(s)
__global__ __launch_bounds__(256) void k4_ns(const float* __restrict__ x,
                                             const float* __restrict__ sm,
                                             const float* __restrict__ a_state,
                                             unsigned short* __restrict__ xb,
                                             float* __restrict__ out2){
  __shared__ alignas(16) unsigned short Xs[128*72];
  __shared__ alignas(16) unsigned short Ss[64*72];
  const int lin = blockIdx.x;
  const int tb = lin & 31, h = (lin >> 5) & 15, b = lin >> 9;
  const int tid = threadIdx.x;
  const int lane = tid & 63, w = tid >> 6;
  const int l15 = lane & 15, l4 = lane >> 4;

  { // stage sm[h] (f32) -> Ss bf16 (row stride 72)
    const float* src = sm + (size_t)h*4096;
    #pragma unroll
    for (int cc = 0; cc < 4; ++cc){
      int c = cc*256 + tid;                // 1024 chunks of 4 floats
      int s = c >> 4, c4 = c & 15;
      float4 v = *(const float4*)&src[s*64 + c4*4];
      uint2 pk = make_uint2(f2bf(v.x) | (f2bf(v.y)<<16), f2bf(v.z) | (f2bf(v.w)<<16));
      *(uint2*)&Ss[s*72 + c4*4] = pk;
    }
  }
  { // stage x slice -> Xs bf16 (stride 72) and xb global (row-major, 16B granules)
    const int row0 = b*Tz + tb*128;
    #pragma unroll
    for (int it = 0; it < 4; ++it){
      int id = it*256 + tid;               // 1024 chunks of 8 floats
      int r = id >> 3, c8 = id & 7;
      const float* px = x + (size_t)(row0 + r)*1024 + h*64 + c8*8;
      float4 v0 = *(const float4*)px, v1 = *(const float4*)(px + 4);
      uint4 pk;
      pk.x = f2bf(v0.x) | (f2bf(v0.y)<<16);
      pk.y = f2bf(v0.z) | (f2bf(v0.w)<<16);
      pk.z = f2bf(v1.x) | (f2bf(v1.y)<<16);
      pk.w = f2bf(v1.z) | (f2bf(v1.w)<<16);
      *(uint4*)&Xs[r*72 + c8*8] = pk;
      *(uint4*)(xb + (size_t)(row0 + r)*1024 + h*64 + c8*8) = pk;
    }
  }
  __syncthreads();

  // acc[i][j]: swapped layout -> D regs = s, D cols(l15) = t
  f32x4 acc[2][4];
  #pragma unroll
  for (int j = 0; j < 4; ++j){
    float4 as4 = *(const float4*)&a_state[(h*4 + b)*64 + j*16 + l4*4];
    f32x4 a0; a0[0]=as4.x; a0[1]=as4.y; a0[2]=as4.z; a0[3]=as4.w;
    acc[0][j] = a0; acc[1][j] = a0;
  }
  #pragma unroll
  for (int kk = 0; kk < 2; ++kk){
    short8 a[2], bb[4];
    #pragma unroll
    for (int i = 0; i < 2; ++i)
      a[i] = *(const short8*)(&Xs[(w*32 + i*16 + l15)*72 + kk*32 + l4*8]);
    #pragma unroll
    for (int j = 0; j < 4; ++j)
      bb[j] = *(const short8*)(&Ss[(j*16 + l15)*72 + kk*32 + l4*8]);
    #pragma unroll
    for (int i = 0; i < 2; ++i)
      #pragma unroll
      for (int j = 0; j < 4; ++j)
        acc[i][j] = __builtin_amdgcn_mfma_f32_16x16x32_bf16(bb[j], a[i], acc[i][j], 0, 0, 0);
  }
  const size_t base = (size_t)h*1048576 + ((size_t)b*4096 + tb*128)*64;
  #pragma unroll
  for (int i = 0; i < 2; ++i)
    #pragma unroll
    for (int j = 0; j < 4; ++j){
      float4 o = make_float4(acc[i][j][0], acc[i][j][1], acc[i][j][2], acc[i][j][3]);
      *(float4*)(out2 + base + (size_t)(w*32 + i*16 + l15)*64 + j*16 + l4*4) = o;
    }
}

// ---------------- K5: out = xb @ Wb^T + const  (R3-proven schedule) -------------------
// 256x256 tile, BK=32, 512 thr (8 waves 2Mx4N), 4 LDS buffers, counted vmcnt(8),
// XOR-swizzled LDS: slot16 = (r*4+g) ^ (r&7)  (inverse applied on global source).
__global__ __launch_bounds__(512, 2) void k5_gemm(const unsigned short* __restrict__ xb,
                                                  const unsigned short* __restrict__ Wb,
                                                  const float* __restrict__ constb,
                                                  float* __restrict__ out){
  __shared__ alignas(16) unsigned short lds[4][2][8192];   // [buf][A/B][256 rows x 32 bf16]
  const int blk = blockIdx.x;
  const int swz = (blk & 7)*32 + (blk >> 3);     // 256 blocks, 8 XCD chunks of 32
  const int bm = (swz >> 2)*256, bn = (swz & 3)*256;
  const int tid = threadIdx.x;
  const int lane = tid & 63, w = tid >> 6;       // 8 waves
  const int l15 = lane & 15, l4 = lane >> 4;
  const int wr = w >> 2, wc = w & 3;             // 2 (M) x 4 (N)

  // staging source mapping: linear slot L -> logical (row r, 16B-seg g)
  const unsigned short* srcA[2];
  const unsigned short* srcB[2];
  #pragma unroll
  for (int q = 0; q < 2; ++q){
    int L = q*512 + w*64 + lane;
    int b = ((L>>2)&1) ^ ((L>>4)&1);
    int r = (L>>3)*2 + b;
    int g = (L&3) ^ ((((L>>3)&1)<<1) | b);
    srcA[q] = xb + (size_t)(bm + r)*1024 + g*8;
    srcB[q] = Wb + (size_t)(bn + r)*1024 + g*8;
  }
  const int dstoff = w*64*8;                      // shorts; + q*4096
  const int lane_off = ((l15*4 + l4) ^ (l15 & 7))*8;  // swizzled frag offset (shorts)

  // prologue: stage tiles 0,1,2 (12 GLL/thread)
  #pragma unroll
  for (int t = 0; t < 3; ++t){
    #pragma unroll
    for (int q = 0; q < 2; ++q) GLL16(srcA[q] + t*32, &lds[t][0][q*4096 + dstoff]);
    #pragma unroll
    for (int q = 0; q < 2; ++q) GLL16(srcB[q] + t*32, &lds[t][1][q*4096 + dstoff]);
  }
  asm volatile("s_waitcnt vmcnt(8)" ::: "memory");
  __builtin_amdgcn_s_barrier();
  asm volatile("" ::: "memory");

  f32x4 acc[8][4] = {};

  for (int t = 0; t < 32; ++t){
    const unsigned short* At = &lds[t & 3][0][0];
    const unsigned short* Bt = &lds[t & 3][1][0];
    const int ts = (t + 3) & 3;
    short8 bfr[4], afr[4];
    // ---- phase A: B-frags + A-frags 0..3, stage A of tile t+3, 16 MFMA
    #pragma unroll
    for (int j = 0; j < 4; ++j)
      bfr[j] = *(const short8*)(Bt + (wc*64 + j*16)*32 + lane_off);
    #pragma unroll
    for (int i = 0; i < 4; ++i)
      afr[i] = *(const short8*)(At + (wr*128 + i*16)*32 + lane_off);
    if (t < 29){
      #pragma unroll
      for (int q = 0; q < 2; ++q) GLL16(srcA[q] + (t+3)*32, &lds[ts][0][q*4096 + dstoff]);
    }
    __builtin_amdgcn_s_setprio(1);
    #pragma unroll
    for (int i = 0; i < 4; ++i)
      #pragma unroll
      for (int j = 0; j < 4; ++j)
        acc[i][j] = __builtin_amdgcn_mfma_f32_16x16x32_bf16(bfr[j], afr[i], acc[i][j], 0, 0, 0);
    __builtin_amdgcn_s_setprio(0);
    // ---- phase B: A-frags 4..7, stage B of tile t+3, 16 MFMA
    #pragma unroll
    for (int i = 0; i < 4; ++i)
      afr[i] = *(const short8*)(At + (wr*128 + (4 + i)*16)*32 + lane_off);
    if (t < 29){
      #pragma unroll
      for (int q = 0; q < 2; ++q) GLL16(srcB[q] + (t+3)*32, &lds[ts][1][q*4096 + dstoff]);
    }
    __builtin_amdgcn_s_setprio(1);
    #pragma unroll
    for (int i = 0; i < 4; ++i)
      #pragma unroll
      for (int j = 0; j < 4; ++j)
        acc[4+i][j] = __builtin_amdgcn_mfma_f32_16x16x32_bf16(bfr[j], afr[i], acc[4+i][j], 0, 0, 0);
    __builtin_amdgcn_s_setprio(0);
    // ---- tile boundary: counted vmcnt (tiles t+2,t+3 stay in flight), barrier
    if (t < 29)       asm volatile("s_waitcnt vmcnt(8)" ::: "memory");
    else if (t == 29) asm volatile("s_waitcnt vmcnt(4)" ::: "memory");
    else if (t == 30) asm volatile("s_waitcnt vmcnt(0)" ::: "memory");
    if (t < 31){
      __builtin_amdgcn_s_barrier();
      asm volatile("" ::: "memory");
    }
  }

  // epilogue: D cols(l15)=t-row, regs(l4*4+q)=e-col
  const int bb = bm >> 12;
  #pragma unroll
  for (int j = 0; j < 4; ++j){
    int n0 = bn + wc*64 + j*16 + l4*4;
    float4 cv = *(const float4*)&constb[bb*1024 + n0];
    #pragma unroll
    for (int i = 0; i < 8; ++i){
      int trow = bm + wr*128 + i*16 + l15;
      float4 o = make_float4(acc[i][j][0] + cv.x, acc[i][j][1] + cv.y,
                             acc[i][j][2] + cv.z, acc[i][j][3] + cv.w);
      *(float4*)(out + (size_t)trow*1024 + n0) = o;
    }
  }
}

extern "C" void kernel_launch(void* const* d_in, const int* in_sizes, int n_in,
                              void* d_out, int out_size, void* d_ws, size_t ws_size,
                              hipStream_t stream){
  const float* x     = (const float*)d_in[0];
  const float* state = (const float*)d_in[1];
  const float* A_w   = (const float*)d_in[2];
  const float* A_b   = (const float*)d_in[3];
  const float* C_w   = (const float*)d_in[4];
  const float* C_b   = (const float*)d_in[5];
  const float* sm    = (const float*)d_in[6];
  const float* Wo    = (const float*)d_in[7];
  const float* bo    = (const float*)d_in[8];
  float* out  = (float*)d_out;
  float* out2 = out + (size_t)MTz*Ez;

  char* ws = (char*)d_ws;
  float* a_state          = (float*)(ws + 0);                 //  16 KiB
  float* constb           = (float*)(ws + 16384);             //  16 KiB
  unsigned short* Wb      = (unsigned short*)(ws + 32768);    //   2 MiB
  unsigned short* xb      = (unsigned short*)(ws + 2129920);  //  32 MiB

  pre_all<<<260, 256, 0, stream>>>(state, A_w, A_b, C_w, C_b, sm, Wo, bo,
                                   a_state, constb, Wb);
  k4_ns<<<2048, 256, 0, stream>>>(x, sm, a_state, xb, out2);
  k5_gemm<<<256, 512, 0, stream>>>(xb, Wb, constb, out);
}